// Round 13
// baseline (188.621 us; speedup 1.0000x reference)
//
#include <hip/hip_runtime.h>
#include <hip/hip_bf16.h>

#define NGROUPS 8   // L=2 labels * S=4 sessions
#define DIM 128
// per-replica layout (floats): [0,1024) sums[8][128], [1024,2048) wsums[8][128], [2048,2056) counts[8]
#define WS_FLOATS 2056
#define NREP 16     // global atomic replicas to cut same-address chains

// x + dpp(x): one step of a VALU-only wave reduction (no LDS pipe)
template <int CTRL>
__device__ __forceinline__ float dpp_add(float x) {
    int s = __builtin_amdgcn_update_dpp(0, __float_as_int(x), CTRL, 0xF, 0xF, true);
    return x + __int_as_float(s);
}

// 64-lane sum; lane 63 ends with the total. 1/max(sqrt,eps) via rsq + cap,
// broadcast to an SGPR with readlane.
__device__ __forceinline__ float wave_rnorm(float ss) {
    float r = ss;
    r = dpp_add<0x111>(r);  // row_shr:1
    r = dpp_add<0x112>(r);  // row_shr:2
    r = dpp_add<0x114>(r);  // row_shr:4
    r = dpp_add<0x118>(r);  // row_shr:8
    r = dpp_add<0x142>(r);  // row_bcast:15
    r = dpp_add<0x143>(r);  // row_bcast:31  -> lane 63 holds the total
    float inv = fminf(__builtin_amdgcn_rsqf(r), 1e8f);  // 1e8 == 1/eps cap
    return __int_as_float(__builtin_amdgcn_readlane(__float_as_int(inv), 63));
}

// G is SGPR (uniform) -> scalar branch chain; only the owning group's
// 4 v_fmac/v_add + 1 s_add execute. No divergence (s_cbranch).
#define ACCUM_ROW_BR(G, V, RN)                                           \
    {                                                                    \
        _Pragma("unroll")                                                \
        for (int q = 0; q < NGROUPS; ++q) {                              \
            if ((G) == q) {                                              \
                cnt[q] += 1;                                             \
                sa[q][0] += (V).x;                                       \
                sa[q][1] += (V).y;                                       \
                wa[q][0] = fmaf((RN), (V).x, wa[q][0]);                  \
                wa[q][1] = fmaf((RN), (V).y, wa[q][1]);                  \
            }                                                            \
        }                                                                \
    }

// one tile = 4 rows (explicit names, compile-time indexing only).
#define LOADT4(V0, V1, V2, V3, LB, SE, T)                                \
    {                                                                    \
        const int rr = ((T) * NW + wid) * 4;                             \
        V0 = feat2[(size_t)rr * 64 + lane];                              \
        V1 = feat2[(size_t)(rr + 1) * 64 + lane];                        \
        V2 = feat2[(size_t)(rr + 2) * 64 + lane];                        \
        V3 = feat2[(size_t)(rr + 3) * 64 + lane];                        \
        LB = lab4[rr >> 2];                                              \
        SE = ses4[rr >> 2];                                              \
    }

// 4 independent DPP/rsq/readlane chains interleave; then branch accumulates.
#define COMPT4(V0, V1, V2, V3, LB, SE)                                   \
    {                                                                    \
        float ss0 = fmaf((V0).x, (V0).x, (V0).y * (V0).y);               \
        float ss1 = fmaf((V1).x, (V1).x, (V1).y * (V1).y);               \
        float ss2 = fmaf((V2).x, (V2).x, (V2).y * (V2).y);               \
        float ss3 = fmaf((V3).x, (V3).x, (V3).y * (V3).y);               \
        float rn0 = wave_rnorm(ss0);                                     \
        float rn1 = wave_rnorm(ss1);                                     \
        float rn2 = wave_rnorm(ss2);                                     \
        float rn3 = wave_rnorm(ss3);                                     \
        const int g0 = (LB).x * 4 + (SE).x;                              \
        const int g1 = (LB).y * 4 + (SE).y;                              \
        const int g2 = (LB).z * 4 + (SE).z;                              \
        const int g3 = (LB).w * 4 + (SE).w;                              \
        ACCUM_ROW_BR(g0, (V0), rn0);                                     \
        ACCUM_ROW_BR(g1, (V1), rn1);                                     \
        ACCUM_ROW_BR(g2, (V2), rn2);                                     \
        ACCUM_ROW_BR(g3, (V3), rn3);                                     \
    }

// 256 threads, 8 waves/SIMD. R12 structure with 4-row tiles:
// depth-2 fixed-role prefetch, branch accumulate, 32-VGPR accumulators.
__global__ __launch_bounds__(256, 8)
void csca_accum_kernel(const float2* __restrict__ feat2,
                       const int* __restrict__ labels,
                       const int* __restrict__ sessions,
                       float* __restrict__ gws, int B) {
    __shared__ float s_all[WS_FLOATS];
    for (int i = threadIdx.x; i < WS_FLOATS; i += 256) s_all[i] = 0.0f;
    __syncthreads();

    const int lane = threadIdx.x & 63;
    const int wid = __builtin_amdgcn_readfirstlane(blockIdx.x * 4 + (threadIdx.x >> 6));
    const int NW = gridDim.x * 4;   // total waves (8192)

    const int4* lab4 = (const int4*)labels;
    const int4* ses4 = (const int4*)sessions;

    float sa[NGROUPS][2], wa[NGROUPS][2];
    int cnt[NGROUPS];               // scalar (g comparisons are uniform)
#pragma unroll
    for (int q = 0; q < NGROUPS; ++q) {
        sa[q][0] = 0.0f; sa[q][1] = 0.0f; wa[q][0] = 0.0f; wa[q][1] = 0.0f;
        cnt[q] = 0;
    }

    const int fI = B / (NW * 4);    // 32 for B=1M
    float2 a0, a1, a2, a3, b0, b1, b2, b3;
    int4 alb, ase, blb, bse;

    if (fI > 0) LOADT4(a0, a1, a2, a3, alb, ase, 0);
    int it = 0;
    for (; it + 3 < fI; it += 2) {
        LOADT4(b0, b1, b2, b3, blb, bse, it + 1);   // prefetch before A's chains
        COMPT4(a0, a1, a2, a3, alb, ase);
        LOADT4(a0, a1, a2, a3, alb, ase, it + 2);   // prefetch before B's chains
        COMPT4(b0, b1, b2, b3, blb, bse);
    }
    if (it < fI) {
        if (it + 1 < fI) {
            LOADT4(b0, b1, b2, b3, blb, bse, it + 1);
            COMPT4(a0, a1, a2, a3, alb, ase);
            COMPT4(b0, b1, b2, b3, blb, bse);
        } else {
            COMPT4(a0, a1, a2, a3, alb, ase);
        }
    }

    // tail rows (empty when B % (NW*4) == 0; kept for generality)
    for (int row = fI * NW * 4 + wid; row < B; row += NW) {
        float2 v = feat2[(size_t)row * 64 + lane];
        int g = __builtin_amdgcn_readfirstlane(labels[row] * 4 + sessions[row]);
        float ss = fmaf(v.x, v.x, v.y * v.y);
        float rn = wave_rnorm(ss);
        ACCUM_ROW_BR(g, v, rn);
    }

    // end-of-kernel block reduction (LDS atomics OK here: once, not per-row)
#pragma unroll
    for (int q = 0; q < NGROUPS; ++q) {
        atomicAdd(&s_all[q * DIM + 2 * lane],            sa[q][0]);
        atomicAdd(&s_all[q * DIM + 2 * lane + 1],        sa[q][1]);
        atomicAdd(&s_all[1024 + q * DIM + 2 * lane],     wa[q][0]);
        atomicAdd(&s_all[1024 + q * DIM + 2 * lane + 1], wa[q][1]);
    }
    if (lane == 0) {
#pragma unroll
        for (int q = 0; q < NGROUPS; ++q)
            atomicAdd(&s_all[2048 + q], (float)cnt[q]);
    }
    __syncthreads();

    float* rep = gws + (size_t)(blockIdx.x & (NREP - 1)) * WS_FLOATS;
    for (int i = threadIdx.x; i < WS_FLOATS; i += 256) atomicAdd(&rep[i], s_all[i]);
}

__global__ __launch_bounds__(256)
void csca_finalize_kernel(const float* __restrict__ gws, float* __restrict__ out, float invB) {
    __shared__ float red[WS_FLOATS];
    for (int i = threadIdx.x; i < WS_FLOATS; i += 256) {
        float s = 0.0f;
#pragma unroll
        for (int r = 0; r < NREP; ++r) s += gws[(size_t)r * WS_FLOATS + i];
        red[i] = s;
    }
    __syncthreads();

    if (threadIdx.x < 64) {
        const int lane = threadIdx.x;
        const float* sums  = red;
        const float* wsums = red + 1024;
        const float* cnts  = red + 2048;
        __shared__ float c_lds[NGROUPS][DIM];
        float cnorm2[NGROUPS];
        float cos_sum = 0.0f;

#pragma unroll
        for (int g = 0; g < NGROUPS; ++g) {
            float invc = 1.0f / cnts[g];
            float c0 = sums[g * DIM + lane] * invc;
            float c1 = sums[g * DIM + 64 + lane] * invc;
            c_lds[g][lane] = c0;
            c_lds[g][64 + lane] = c1;
            float w0 = wsums[g * DIM + lane];
            float w1 = wsums[g * DIM + 64 + lane];
            float pcc = c0 * c0 + c1 * c1;
            float pwc = w0 * c0 + w1 * c1;
#pragma unroll
            for (int m = 1; m < 64; m <<= 1) {
                pcc += __shfl_xor(pcc, m);
                pwc += __shfl_xor(pwc, m);
            }
            cnorm2[g] = pcc;
            cos_sum += pwc / fmaxf(sqrtf(pcc), 1e-8f);
        }
        float center_loss = 1.0f - cos_sum * invB;

        float align = 0.0f;
#pragma unroll
        for (int y = 0; y < 2; ++y) {
            float p0 = 0.0f, p1 = 0.0f;
#pragma unroll
            for (int s = 0; s < 4; ++s) {
                p0 += c_lds[4 * y + s][lane];
                p1 += c_lds[4 * y + s][64 + lane];
            }
            p0 *= 0.25f; p1 *= 0.25f;
            float ppp = p0 * p0 + p1 * p1;
#pragma unroll
            for (int m = 1; m < 64; m <<= 1) ppp += __shfl_xor(ppp, m);
            float pn = fmaxf(sqrtf(ppp), 1e-8f);
            float pc = 0.0f;
#pragma unroll
            for (int s = 0; s < 4; ++s) {
                float d = c_lds[4 * y + s][lane] * p0 + c_lds[4 * y + s][64 + lane] * p1;
#pragma unroll
                for (int m = 1; m < 64; m <<= 1) d += __shfl_xor(d, m);
                float cs = d / (fmaxf(sqrtf(cnorm2[4 * y + s]), 1e-8f) * pn);
                pc += 1.0f - cs;
            }
            align = (align + pc) * 0.25f;  // running /S division, faithful to reference
        }

        if (lane == 0) {
            out[0] = center_loss + align;
            out[1] = center_loss;
            out[2] = align;
        }
    }
}

extern "C" void kernel_launch(void* const* d_in, const int* in_sizes, int n_in,
                              void* d_out, int out_size, void* d_ws, size_t ws_size,
                              hipStream_t stream) {
    const float* feat = (const float*)d_in[0];
    const int* labels = (const int*)d_in[1];
    const int* sessions = (const int*)d_in[2];
    const int B = in_sizes[1];          // 1048576 (features are B x 128)
    float* gws = (float*)d_ws;

    hipMemsetAsync(gws, 0, (size_t)NREP * WS_FLOATS * sizeof(float), stream);

    csca_accum_kernel<<<2048, 256, 0, stream>>>((const float2*)feat, labels, sessions, gws, B);
    csca_finalize_kernel<<<1, 256, 0, stream>>>(gws, (float*)d_out, 1.0f / (float)B);
}

// Round 14
// 178.726 us; speedup vs baseline: 1.0554x; 1.0554x over previous
//
#include <hip/hip_runtime.h>
#include <hip/hip_bf16.h>

#define NGROUPS 8   // L=2 labels * S=4 sessions
#define DIM 128
#define WS_FLOATS 2056          // per-block partial: sums[8][128] wsums[8][128] counts[8]
#define NBLK 2048               // accum grid
// workspace: P[NBLK][WS_FLOATS] partials, then F[WS_FLOATS] finals
#define F_OFFSET ((size_t)NBLK * WS_FLOATS)

// x + dpp(x): one step of a VALU-only wave reduction (no LDS pipe)
template <int CTRL>
__device__ __forceinline__ float dpp_add(float x) {
    int s = __builtin_amdgcn_update_dpp(0, __float_as_int(x), CTRL, 0xF, 0xF, true);
    return x + __int_as_float(s);
}

// 64-lane sum; lane 63 ends with the total. 1/max(sqrt,eps) via rsq + cap,
// broadcast to an SGPR with readlane.
__device__ __forceinline__ float wave_rnorm(float ss) {
    float r = ss;
    r = dpp_add<0x111>(r);  // row_shr:1
    r = dpp_add<0x112>(r);  // row_shr:2
    r = dpp_add<0x114>(r);  // row_shr:4
    r = dpp_add<0x118>(r);  // row_shr:8
    r = dpp_add<0x142>(r);  // row_bcast:15
    r = dpp_add<0x143>(r);  // row_bcast:31  -> lane 63 holds the total
    float inv = fminf(__builtin_amdgcn_rsqf(r), 1e8f);  // 1e8 == 1/eps cap
    return __int_as_float(__builtin_amdgcn_readlane(__float_as_int(inv), 63));
}

// G is SGPR (uniform) -> scalar branch chain; only the owning group's
// 4 v_fmac/v_add + 1 s_add execute. No divergence (s_cbranch).
#define ACCUM_ROW_BR(G, V, RN)                                           \
    {                                                                    \
        _Pragma("unroll")                                                \
        for (int q = 0; q < NGROUPS; ++q) {                              \
            if ((G) == q) {                                              \
                cnt[q] += 1;                                             \
                sa[q][0] += (V).x;                                       \
                sa[q][1] += (V).y;                                       \
                wa[q][0] = fmaf((RN), (V).x, wa[q][0]);                  \
                wa[q][1] = fmaf((RN), (V).y, wa[q][1]);                  \
            }                                                            \
        }                                                                \
    }

// one tile = 2 rows. Fixed-role load/compute macros (no register rotation).
#define LOADT(V0, V1, LB, SE, T)                                         \
    {                                                                    \
        const int rr = ((T) * NW + wid) * 2;                             \
        V0 = feat2[(size_t)rr * 64 + lane];                              \
        V1 = feat2[(size_t)(rr + 1) * 64 + lane];                        \
        LB = lab2[rr >> 1];                                              \
        SE = ses2[rr >> 1];                                              \
    }

#define COMPT(V0, V1, LB, SE)                                            \
    {                                                                    \
        float ss0 = fmaf((V0).x, (V0).x, (V0).y * (V0).y);               \
        float ss1 = fmaf((V1).x, (V1).x, (V1).y * (V1).y);               \
        float rn0 = wave_rnorm(ss0);                                     \
        float rn1 = wave_rnorm(ss1);                                     \
        const int g0 = (LB).x * 4 + (SE).x;                              \
        const int g1 = (LB).y * 4 + (SE).y;                              \
        ACCUM_ROW_BR(g0, (V0), rn0);                                     \
        ACCUM_ROW_BR(g1, (V1), rn1);                                     \
    }

// 256 threads, 8 waves/SIMD. Loop bit-identical to R12 (depth-2 prefetch,
// branch accumulate). Epilogue: NON-ATOMIC per-block store (no global atomics).
__global__ __launch_bounds__(256, 8)
void csca_accum_kernel(const float2* __restrict__ feat2,
                       const int* __restrict__ labels,
                       const int* __restrict__ sessions,
                       float* __restrict__ gws, int B) {
    __shared__ float s_all[WS_FLOATS];
    for (int i = threadIdx.x; i < WS_FLOATS; i += 256) s_all[i] = 0.0f;
    __syncthreads();

    const int lane = threadIdx.x & 63;
    const int wid = __builtin_amdgcn_readfirstlane(blockIdx.x * 4 + (threadIdx.x >> 6));
    const int NW = gridDim.x * 4;   // total waves (8192)

    const int2* lab2 = (const int2*)labels;
    const int2* ses2 = (const int2*)sessions;

    float sa[NGROUPS][2], wa[NGROUPS][2];
    int cnt[NGROUPS];               // scalar (g comparisons are uniform)
#pragma unroll
    for (int q = 0; q < NGROUPS; ++q) {
        sa[q][0] = 0.0f; sa[q][1] = 0.0f; wa[q][0] = 0.0f; wa[q][1] = 0.0f;
        cnt[q] = 0;
    }

    const int fI = B / (NW * 2);    // 64 for B=1M
    float2 a0, a1, b0, b1;
    int2 alb, ase, blb, bse;

    if (fI > 0) LOADT(a0, a1, alb, ase, 0);
    int it = 0;
    for (; it + 3 < fI; it += 2) {
        LOADT(b0, b1, blb, bse, it + 1);   // prefetch before A's chain
        COMPT(a0, a1, alb, ase);
        LOADT(a0, a1, alb, ase, it + 2);   // prefetch before B's chain
        COMPT(b0, b1, blb, bse);
    }
    if (it < fI) {
        if (it + 1 < fI) {
            LOADT(b0, b1, blb, bse, it + 1);
            COMPT(a0, a1, alb, ase);
            COMPT(b0, b1, blb, bse);
        } else {
            COMPT(a0, a1, alb, ase);
        }
    }

    // tail rows (empty when B % (NW*2) == 0; kept for generality)
    for (int row = fI * NW * 2 + wid; row < B; row += NW) {
        float2 v = feat2[(size_t)row * 64 + lane];
        int g = __builtin_amdgcn_readfirstlane(labels[row] * 4 + sessions[row]);
        float ss = fmaf(v.x, v.x, v.y * v.y);
        float rn = wave_rnorm(ss);
        ACCUM_ROW_BR(g, v, rn);
    }

    // block-level LDS reduction (once per kernel; fine)
#pragma unroll
    for (int q = 0; q < NGROUPS; ++q) {
        atomicAdd(&s_all[q * DIM + 2 * lane],            sa[q][0]);
        atomicAdd(&s_all[q * DIM + 2 * lane + 1],        sa[q][1]);
        atomicAdd(&s_all[1024 + q * DIM + 2 * lane],     wa[q][0]);
        atomicAdd(&s_all[1024 + q * DIM + 2 * lane + 1], wa[q][1]);
    }
    if (lane == 0) {
#pragma unroll
        for (int q = 0; q < NGROUPS; ++q)
            atomicAdd(&s_all[2048 + q], (float)cnt[q]);
    }
    __syncthreads();

    // NON-ATOMIC coalesced store of this block's partials
    float* myP = gws + (size_t)blockIdx.x * WS_FLOATS;
    for (int i = threadIdx.x; i < WS_FLOATS; i += 256) myP[i] = s_all[i];
}

// parallel fold of the NBLK partial vectors: grid (9, 32); block (x) covers
// 256 elements, block (y) covers 64 replicas; 32 atomics/address total.
__global__ __launch_bounds__(256)
void csca_reduce_kernel(const float* __restrict__ gws, float* __restrict__ F) {
    const int i = blockIdx.x * 256 + threadIdx.x;
    if (i >= WS_FLOATS) return;
    const int r0 = blockIdx.y * (NBLK / 32);
    float s = 0.0f;
#pragma unroll 8
    for (int k = 0; k < NBLK / 32; ++k)
        s += gws[(size_t)(r0 + k) * WS_FLOATS + i];
    atomicAdd(&F[i], s);
}

__global__ __launch_bounds__(256)
void csca_finalize_kernel(const float* __restrict__ F, float* __restrict__ out, float invB) {
    __shared__ float red[WS_FLOATS];
    for (int i = threadIdx.x; i < WS_FLOATS; i += 256) red[i] = F[i];
    __syncthreads();

    if (threadIdx.x < 64) {
        const int lane = threadIdx.x;
        const float* sums  = red;
        const float* wsums = red + 1024;
        const float* cnts  = red + 2048;
        __shared__ float c_lds[NGROUPS][DIM];
        float cnorm2[NGROUPS];
        float cos_sum = 0.0f;

#pragma unroll
        for (int g = 0; g < NGROUPS; ++g) {
            float invc = 1.0f / cnts[g];
            float c0 = sums[g * DIM + lane] * invc;
            float c1 = sums[g * DIM + 64 + lane] * invc;
            c_lds[g][lane] = c0;
            c_lds[g][64 + lane] = c1;
            float w0 = wsums[g * DIM + lane];
            float w1 = wsums[g * DIM + 64 + lane];
            float pcc = c0 * c0 + c1 * c1;
            float pwc = w0 * c0 + w1 * c1;
#pragma unroll
            for (int m = 1; m < 64; m <<= 1) {
                pcc += __shfl_xor(pcc, m);
                pwc += __shfl_xor(pwc, m);
            }
            cnorm2[g] = pcc;
            cos_sum += pwc / fmaxf(sqrtf(pcc), 1e-8f);
        }
        float center_loss = 1.0f - cos_sum * invB;

        float align = 0.0f;
#pragma unroll
        for (int y = 0; y < 2; ++y) {
            float p0 = 0.0f, p1 = 0.0f;
#pragma unroll
            for (int s = 0; s < 4; ++s) {
                p0 += c_lds[4 * y + s][lane];
                p1 += c_lds[4 * y + s][64 + lane];
            }
            p0 *= 0.25f; p1 *= 0.25f;
            float ppp = p0 * p0 + p1 * p1;
#pragma unroll
            for (int m = 1; m < 64; m <<= 1) ppp += __shfl_xor(ppp, m);
            float pn = fmaxf(sqrtf(ppp), 1e-8f);
            float pc = 0.0f;
#pragma unroll
            for (int s = 0; s < 4; ++s) {
                float d = c_lds[4 * y + s][lane] * p0 + c_lds[4 * y + s][64 + lane] * p1;
#pragma unroll
                for (int m = 1; m < 64; m <<= 1) d += __shfl_xor(d, m);
                float cs = d / (fmaxf(sqrtf(cnorm2[4 * y + s]), 1e-8f) * pn);
                pc += 1.0f - cs;
            }
            align = (align + pc) * 0.25f;  // running /S division, faithful to reference
        }

        if (lane == 0) {
            out[0] = center_loss + align;
            out[1] = center_loss;
            out[2] = align;
        }
    }
}

extern "C" void kernel_launch(void* const* d_in, const int* in_sizes, int n_in,
                              void* d_out, int out_size, void* d_ws, size_t ws_size,
                              hipStream_t stream) {
    const float* feat = (const float*)d_in[0];
    const int* labels = (const int*)d_in[1];
    const int* sessions = (const int*)d_in[2];
    const int B = in_sizes[1];          // 1048576 (features are B x 128)
    float* gws = (float*)d_ws;
    float* F = gws + F_OFFSET;

    // only the small final vector needs zeroing (reduce uses atomicAdd on it)
    hipMemsetAsync(F, 0, WS_FLOATS * sizeof(float), stream);

    csca_accum_kernel<<<NBLK, 256, 0, stream>>>((const float2*)feat, labels, sessions, gws, B);
    csca_reduce_kernel<<<dim3(9, 32), 256, 0, stream>>>(gws, F);
    csca_finalize_kernel<<<1, 256, 0, stream>>>(F, (float*)d_out, 1.0f / (float)B);
}

// Round 15
// 166.907 us; speedup vs baseline: 1.1301x; 1.0708x over previous
//
#include <hip/hip_runtime.h>
#include <hip/hip_bf16.h>

#define NGROUPS 8   // L=2 labels * S=4 sessions
#define DIM 128
#define WS_FLOATS 2056          // per-block partial: sums[8][128] wsums[8][128] counts[8]
#define NBLK 2048               // accum grid
// workspace: P[NBLK][WS_FLOATS] partials, then F[WS_FLOATS] finals
#define F_OFFSET ((size_t)NBLK * WS_FLOATS)

// x + dpp(x): one step of a VALU-only wave reduction (no LDS pipe)
template <int CTRL>
__device__ __forceinline__ float dpp_add(float x) {
    int s = __builtin_amdgcn_update_dpp(0, __float_as_int(x), CTRL, 0xF, 0xF, true);
    return x + __int_as_float(s);
}

// 64-lane sum; lane 63 ends with the total. 1/max(sqrt,eps) via rsq + cap,
// broadcast to an SGPR with readlane.
__device__ __forceinline__ float wave_rnorm(float ss) {
    float r = ss;
    r = dpp_add<0x111>(r);  // row_shr:1
    r = dpp_add<0x112>(r);  // row_shr:2
    r = dpp_add<0x114>(r);  // row_shr:4
    r = dpp_add<0x118>(r);  // row_shr:8
    r = dpp_add<0x142>(r);  // row_bcast:15
    r = dpp_add<0x143>(r);  // row_bcast:31  -> lane 63 holds the total
    float inv = fminf(__builtin_amdgcn_rsqf(r), 1e8f);  // 1e8 == 1/eps cap
    return __int_as_float(__builtin_amdgcn_readlane(__float_as_int(inv), 63));
}

// G is SGPR (uniform) -> scalar branch chain; only the owning group's
// 4 v_fmac/v_add + 1 s_add execute. No divergence (s_cbranch).
#define ACCUM_ROW_BR(G, V, RN)                                           \
    {                                                                    \
        _Pragma("unroll")                                                \
        for (int q = 0; q < NGROUPS; ++q) {                              \
            if ((G) == q) {                                              \
                cnt[q] += 1;                                             \
                sa[q][0] += (V).x;                                       \
                sa[q][1] += (V).y;                                       \
                wa[q][0] = fmaf((RN), (V).x, wa[q][0]);                  \
                wa[q][1] = fmaf((RN), (V).y, wa[q][1]);                  \
            }                                                            \
        }                                                                \
    }

// feat-only tile load: rows CB+2T, CB+2T+1 (contiguous within the chunk)
#define LOADF(V0, V1, CB, T)                                             \
    {                                                                    \
        const int rr = (CB) + 2 * (T);                                   \
        V0 = feat2[(size_t)rr * 64 + lane];                              \
        V1 = feat2[((size_t)rr + 1) * 64 + lane];                        \
    }

// G0/G1 arrive as wave-uniform ints (from v_readlane of the chunk g-vector)
#define COMPT(V0, V1, G0, G1)                                            \
    {                                                                    \
        float ss0 = fmaf((V0).x, (V0).x, (V0).y * (V0).y);               \
        float ss1 = fmaf((V1).x, (V1).x, (V1).y * (V1).y);               \
        float rn0 = wave_rnorm(ss0);                                     \
        float rn1 = wave_rnorm(ss1);                                     \
        ACCUM_ROW_BR((G0), (V0), rn0);                                   \
        ACCUM_ROW_BR((G1), (V1), rn1);                                   \
    }

// 256 threads, 8 waves/SIMD. vs R14 (178.7us): per-iteration s_loads of
// labels/sessions replaced by one per-chunk VECTOR load + v_readlane per row,
// eliminating the per-iteration s_waitcnt lgkmcnt(0) SMEM drain.
__global__ __launch_bounds__(256, 8)
void csca_accum_kernel(const float2* __restrict__ feat2,
                       const int* __restrict__ labels,
                       const int* __restrict__ sessions,
                       float* __restrict__ gws, int B) {
    __shared__ float s_all[WS_FLOATS];
    for (int i = threadIdx.x; i < WS_FLOATS; i += 256) s_all[i] = 0.0f;
    __syncthreads();

    const int lane = threadIdx.x & 63;
    const int wid = __builtin_amdgcn_readfirstlane(blockIdx.x * 4 + (threadIdx.x >> 6));
    const int NW = gridDim.x * 4;   // total waves (8192)

    float sa[NGROUPS][2], wa[NGROUPS][2];
    int cnt[NGROUPS];               // scalar (g comparisons are uniform)
#pragma unroll
    for (int q = 0; q < NGROUPS; ++q) {
        sa[q][0] = 0.0f; sa[q][1] = 0.0f; wa[q][0] = 0.0f; wa[q][1] = 0.0f;
        cnt[q] = 0;
    }

    // chunks of 64 contiguous rows per wave (B = NW*128 -> 2 chunks/wave)
    for (int cb = wid * 64; cb + 63 < B; cb += NW * 64) {
        // one coalesced vector load of this chunk's 64 group ids
        const int g_vec = labels[cb + lane] * 4 + sessions[cb + lane];

        float2 a0, a1, b0, b1;
        LOADF(a0, a1, cb, 0);
        int it = 0;
        for (; it + 3 < 32; it += 2) {
            LOADF(b0, b1, cb, it + 1);        // prefetch before A's chain
            COMPT(a0, a1,
                  __builtin_amdgcn_readlane(g_vec, 2 * it),
                  __builtin_amdgcn_readlane(g_vec, 2 * it + 1));
            LOADF(a0, a1, cb, it + 2);        // prefetch before B's chain
            COMPT(b0, b1,
                  __builtin_amdgcn_readlane(g_vec, 2 * it + 2),
                  __builtin_amdgcn_readlane(g_vec, 2 * it + 3));
        }
        // drain: it == 30 here; tiles 30 and 31 remain (a holds tile 30)
        LOADF(b0, b1, cb, 31);
        COMPT(a0, a1,
              __builtin_amdgcn_readlane(g_vec, 60),
              __builtin_amdgcn_readlane(g_vec, 61));
        COMPT(b0, b1,
              __builtin_amdgcn_readlane(g_vec, 62),
              __builtin_amdgcn_readlane(g_vec, 63));
    }

    // tail rows (rows beyond the last full 64-chunk; empty for B % 64 == 0)
    for (int row = (B & ~63) + wid; row < B; row += NW) {
        float2 v = feat2[(size_t)row * 64 + lane];
        int g = __builtin_amdgcn_readfirstlane(labels[row] * 4 + sessions[row]);
        float ss = fmaf(v.x, v.x, v.y * v.y);
        float rn = wave_rnorm(ss);
        ACCUM_ROW_BR(g, v, rn);
    }

    // block-level LDS reduction (once per kernel; fine)
#pragma unroll
    for (int q = 0; q < NGROUPS; ++q) {
        atomicAdd(&s_all[q * DIM + 2 * lane],            sa[q][0]);
        atomicAdd(&s_all[q * DIM + 2 * lane + 1],        sa[q][1]);
        atomicAdd(&s_all[1024 + q * DIM + 2 * lane],     wa[q][0]);
        atomicAdd(&s_all[1024 + q * DIM + 2 * lane + 1], wa[q][1]);
    }
    if (lane == 0) {
#pragma unroll
        for (int q = 0; q < NGROUPS; ++q)
            atomicAdd(&s_all[2048 + q], (float)cnt[q]);
    }
    __syncthreads();

    // NON-ATOMIC coalesced store of this block's partials
    float* myP = gws + (size_t)blockIdx.x * WS_FLOATS;
    for (int i = threadIdx.x; i < WS_FLOATS; i += 256) myP[i] = s_all[i];
}

// parallel fold of the NBLK partial vectors: grid (9, 32); block (x) covers
// 256 elements, block (y) covers 64 replicas; 32 atomics/address total.
__global__ __launch_bounds__(256)
void csca_reduce_kernel(const float* __restrict__ gws, float* __restrict__ F) {
    const int i = blockIdx.x * 256 + threadIdx.x;
    if (i >= WS_FLOATS) return;
    const int r0 = blockIdx.y * (NBLK / 32);
    float s = 0.0f;
#pragma unroll 8
    for (int k = 0; k < NBLK / 32; ++k)
        s += gws[(size_t)(r0 + k) * WS_FLOATS + i];
    atomicAdd(&F[i], s);
}

__global__ __launch_bounds__(256)
void csca_finalize_kernel(const float* __restrict__ F, float* __restrict__ out, float invB) {
    __shared__ float red[WS_FLOATS];
    for (int i = threadIdx.x; i < WS_FLOATS; i += 256) red[i] = F[i];
    __syncthreads();

    if (threadIdx.x < 64) {
        const int lane = threadIdx.x;
        const float* sums  = red;
        const float* wsums = red + 1024;
        const float* cnts  = red + 2048;
        __shared__ float c_lds[NGROUPS][DIM];
        float cnorm2[NGROUPS];
        float cos_sum = 0.0f;

#pragma unroll
        for (int g = 0; g < NGROUPS; ++g) {
            float invc = 1.0f / cnts[g];
            float c0 = sums[g * DIM + lane] * invc;
            float c1 = sums[g * DIM + 64 + lane] * invc;
            c_lds[g][lane] = c0;
            c_lds[g][64 + lane] = c1;
            float w0 = wsums[g * DIM + lane];
            float w1 = wsums[g * DIM + 64 + lane];
            float pcc = c0 * c0 + c1 * c1;
            float pwc = w0 * c0 + w1 * c1;
#pragma unroll
            for (int m = 1; m < 64; m <<= 1) {
                pcc += __shfl_xor(pcc, m);
                pwc += __shfl_xor(pwc, m);
            }
            cnorm2[g] = pcc;
            cos_sum += pwc / fmaxf(sqrtf(pcc), 1e-8f);
        }
        float center_loss = 1.0f - cos_sum * invB;

        float align = 0.0f;
#pragma unroll
        for (int y = 0; y < 2; ++y) {
            float p0 = 0.0f, p1 = 0.0f;
#pragma unroll
            for (int s = 0; s < 4; ++s) {
                p0 += c_lds[4 * y + s][lane];
                p1 += c_lds[4 * y + s][64 + lane];
            }
            p0 *= 0.25f; p1 *= 0.25f;
            float ppp = p0 * p0 + p1 * p1;
#pragma unroll
            for (int m = 1; m < 64; m <<= 1) ppp += __shfl_xor(ppp, m);
            float pn = fmaxf(sqrtf(ppp), 1e-8f);
            float pc = 0.0f;
#pragma unroll
            for (int s = 0; s < 4; ++s) {
                float d = c_lds[4 * y + s][lane] * p0 + c_lds[4 * y + s][64 + lane] * p1;
#pragma unroll
                for (int m = 1; m < 64; m <<= 1) d += __shfl_xor(d, m);
                float cs = d / (fmaxf(sqrtf(cnorm2[4 * y + s]), 1e-8f) * pn);
                pc += 1.0f - cs;
            }
            align = (align + pc) * 0.25f;  // running /S division, faithful to reference
        }

        if (lane == 0) {
            out[0] = center_loss + align;
            out[1] = center_loss;
            out[2] = align;
        }
    }
}

extern "C" void kernel_launch(void* const* d_in, const int* in_sizes, int n_in,
                              void* d_out, int out_size, void* d_ws, size_t ws_size,
                              hipStream_t stream) {
    const float* feat = (const float*)d_in[0];
    const int* labels = (const int*)d_in[1];
    const int* sessions = (const int*)d_in[2];
    const int B = in_sizes[1];          // 1048576 (features are B x 128)
    float* gws = (float*)d_ws;
    float* F = gws + F_OFFSET;

    // only the small final vector needs zeroing (reduce uses atomicAdd on it)
    hipMemsetAsync(F, 0, WS_FLOATS * sizeof(float), stream);

    csca_accum_kernel<<<NBLK, 256, 0, stream>>>((const float2*)feat, labels, sessions, gws, B);
    csca_reduce_kernel<<<dim3(9, 32), 256, 0, stream>>>(gws, F);
    csca_finalize_kernel<<<1, 256, 0, stream>>>(F, (float*)d_out, 1.0f / (float)B);
}